// Round 1
// baseline (8768.838 us; speedup 1.0000x reference)
//
#include <hip/hip_runtime.h>
#include <math.h>

#define VSEG 50000
#define CH 32
#define KIN 10
#define NB_STATS 256

// ---------- order-preserving float <-> uint encoding (for atomic min/max) ----
static __device__ __forceinline__ unsigned encf(float f) {
    unsigned b = __float_as_uint(f);
    return (b & 0x80000000u) ? ~b : (b | 0x80000000u);
}
static __device__ __forceinline__ float decf(unsigned u) {
    unsigned b = (u & 0x80000000u) ? (u ^ 0x80000000u) : ~u;
    return __uint_as_float(b);
}
#define ENC_NEG_INF 0x007FFFFFu  /* encf(-inf) */
#define ENC_POS_INF 0xFF800000u  /* encf(+inf) */

// ---------------------------- init workspace --------------------------------
__global__ __launch_bounds__(256) void init_ws_k(unsigned* qmax, unsigned* minb,
                                                 float* segsum, float* denom,
                                                 unsigned* cnt, unsigned* wmaxb) {
    int i = blockIdx.x * blockDim.x + threadIdx.x;
    if (i < VSEG * CH) {
        qmax[i] = 0u;              // bits of +0.0f; x >= 0 so int-max works; empty->0
        minb[i] = ENC_POS_INF;     // min identity; empty -> +inf -> finite_or_zero -> 0
        segsum[i] = 0.0f;
    }
    if (i < VSEG) {
        denom[i] = 0.0f;
        cnt[i] = 0u;
        wmaxb[i] = ENC_NEG_INF;    // max identity
    }
}

// ------------------------- stats: moments of inputs --------------------------
// acc layout: [0..9] = sum x_k ; [10..64] = sum x_k*x_l (k<=l), idx = 10 + k*(21-k)/2 + (l-k)
__global__ __launch_bounds__(256) void stats_partial_k(const float* __restrict__ in, int n,
                                                       float* __restrict__ partial) {
    float acc[65];
#pragma unroll
    for (int q = 0; q < 65; ++q) acc[q] = 0.0f;

    for (int i = blockIdx.x * blockDim.x + threadIdx.x; i < n; i += gridDim.x * blockDim.x) {
        const float* ip = in + (size_t)i * KIN;
        float x[KIN];
#pragma unroll
        for (int k = 0; k < KIN; ++k) x[k] = ip[k];
#pragma unroll
        for (int k = 0; k < KIN; ++k) acc[k] += x[k];
#pragma unroll
        for (int k = 0; k < KIN; ++k) {
#pragma unroll
            for (int l = k; l < KIN; ++l)
                acc[10 + k * (21 - k) / 2 + (l - k)] += x[k] * x[l];
        }
    }

    __shared__ float red[4][65];
    int lane = threadIdx.x & 63, wid = threadIdx.x >> 6;
#pragma unroll
    for (int q = 0; q < 65; ++q) {
        float v = acc[q];
#pragma unroll
        for (int off = 32; off > 0; off >>= 1) v += __shfl_down(v, off, 64);
        if (lane == 0) red[wid][q] = v;
    }
    __syncthreads();
    if (threadIdx.x < 65)
        partial[blockIdx.x * 65 + threadIdx.x] =
            red[0][threadIdx.x] + red[1][threadIdx.x] + red[2][threadIdx.x] + red[3][threadIdx.x];
}

// finalize: per-channel BN scale/shift for both branches.
// ss layout: [0..31]=scale_v [32..63]=shift_v [64..95]=scale_u [96..127]=shift_u
__global__ __launch_bounds__(128) void stats_finalize_k(
    const float* __restrict__ partial, int nb, int n,
    const float* __restrict__ Wlin, const float* __restrict__ blin,
    const float* __restrict__ g1, const float* __restrict__ be1,
    const float* __restrict__ Ww1, const float* __restrict__ bw1,
    const float* __restrict__ g2, const float* __restrict__ be2,
    float* __restrict__ ss) {
    __shared__ double tot[65];
    int t = threadIdx.x;
    if (t < 65) {
        double s = 0.0;
        for (int b = 0; b < nb; ++b) s += (double)partial[b * 65 + t];
        tot[t] = s;
    }
    __syncthreads();
    if (t < 64) {
        int c = t & 31;
        const float* W = (t < 32) ? Wlin : Ww1;
        double bb = (double)((t < 32) ? blin[c] : bw1[c]);
        double g  = (double)((t < 32) ? g1[c] : g2[c]);
        double be = (double)((t < 32) ? be1[c] : be2[c]);
        double eps = (t < 32) ? 1e-3 : 1e-5;
        double invN = 1.0 / (double)n;
        double m0 = 0.0;
        for (int k = 0; k < KIN; ++k) m0 += tot[k] * (double)W[k * CH + c];
        m0 *= invN;
        double q0 = 0.0;
        for (int k = 0; k < KIN; ++k)
            for (int l = k; l < KIN; ++l) {
                int qi = 10 + k * (21 - k) / 2 + (l - k);
                double coef = (k == l) ? 1.0 : 2.0;
                q0 += coef * tot[qi] * (double)W[k * CH + c] * (double)W[l * CH + c];
            }
        q0 *= invN;
        double var = q0 - m0 * m0;
        double mean = m0 + bb;
        double sc = g / sqrt(var + eps);
        float scale = (float)sc;
        float shift = (float)(be - mean * sc);
        if (t < 32) { ss[c] = scale; ss[32 + c] = shift; }
        else        { ss[64 + c] = scale; ss[96 + c] = shift; }
    }
}

// ------------------------------- point pass A --------------------------------
__global__ __launch_bounds__(256) void pass2_k(
    const float* __restrict__ in, const int* __restrict__ idx, int n,
    const float* __restrict__ Wlin, const float* __restrict__ blin,
    const float* __restrict__ Ww1, const float* __restrict__ bw1,
    const float* __restrict__ Ww2, const float* __restrict__ bw2,
    const float* __restrict__ ss,
    float* __restrict__ out, float* __restrict__ weight,
    unsigned* __restrict__ qmax, unsigned* __restrict__ minb,
    unsigned* __restrict__ wmaxb, unsigned* __restrict__ cnt) {
    __shared__ float sWlin[KIN * CH], sWw1[KIN * CH];
    __shared__ float sblin[CH], sbw1[CH], sWw2[CH], sss[128];
    __shared__ float sbw2;
    for (int i = threadIdx.x; i < KIN * CH; i += blockDim.x) { sWlin[i] = Wlin[i]; sWw1[i] = Ww1[i]; }
    for (int i = threadIdx.x; i < CH; i += blockDim.x) { sblin[i] = blin[i]; sbw1[i] = bw1[i]; sWw2[i] = Ww2[i]; }
    for (int i = threadIdx.x; i < 128; i += blockDim.x) sss[i] = ss[i];
    if (threadIdx.x == 0) sbw2 = bw2[0];
    __syncthreads();

    int nidx = blockIdx.x * blockDim.x + threadIdx.x;
    if (nidx >= n) return;

    const float* ip = in + (size_t)nidx * KIN;
    float x[KIN];
#pragma unroll
    for (int k = 0; k < KIN; ++k) x[k] = ip[k];

    float v[CH], u[CH];
#pragma unroll
    for (int c = 0; c < CH; ++c) { v[c] = sblin[c]; u[c] = sbw1[c]; }
#pragma unroll
    for (int k = 0; k < KIN; ++k) {
        float f = x[k];
#pragma unroll
        for (int c = 0; c < CH; ++c) {
            v[c] = fmaf(f, sWlin[k * CH + c], v[c]);
            u[c] = fmaf(f, sWw1[k * CH + c], u[c]);
        }
    }

    int seg = idx[nidx];
    float w = sbw2;
    float xo[CH];
#pragma unroll
    for (int c = 0; c < CH; ++c) {
        float nv = fmaf(v[c], sss[c], sss[32 + c]);
        float xx = fmaxf(nv, 0.0f);
        xo[c] = xx;
        float hu = fmaxf(fmaf(u[c], sss[64 + c], sss[96 + c]), 0.0f);
        w = fmaf(hu, sWw2[c], w);
        atomicMax((int*)qmax + (size_t)seg * CH + c, __float_as_int(xx));
        atomicMin(minb + (size_t)seg * CH + c, encf(nv));
    }

    float4* op = (float4*)(out + (size_t)nidx * 64);
#pragma unroll
    for (int c8 = 0; c8 < 8; ++c8)
        op[c8] = make_float4(xo[4 * c8], xo[4 * c8 + 1], xo[4 * c8 + 2], xo[4 * c8 + 3]);

    weight[nidx] = w;
    atomicMax(wmaxb + seg, encf(w));
    atomicAdd(cnt + seg, 1u);
}

// ------------------------------- point pass B --------------------------------
__global__ __launch_bounds__(256) void pass3_k(
    const float* __restrict__ in, const int* __restrict__ idx, int n,
    const float* __restrict__ Wlin, const float* __restrict__ blin,
    const float* __restrict__ weight, const unsigned* __restrict__ wmaxb,
    float* __restrict__ denom, float* __restrict__ segsum) {
    __shared__ float sWlin[KIN * CH], sblin[CH];
    for (int i = threadIdx.x; i < KIN * CH; i += blockDim.x) sWlin[i] = Wlin[i];
    for (int i = threadIdx.x; i < CH; i += blockDim.x) sblin[i] = blin[i];
    __syncthreads();

    int nidx = blockIdx.x * blockDim.x + threadIdx.x;
    if (nidx >= n) return;

    const float* ip = in + (size_t)nidx * KIN;
    float x[KIN];
#pragma unroll
    for (int k = 0; k < KIN; ++k) x[k] = ip[k];

    float v[CH];
#pragma unroll
    for (int c = 0; c < CH; ++c) v[c] = sblin[c];
#pragma unroll
    for (int k = 0; k < KIN; ++k) {
        float f = x[k];
#pragma unroll
        for (int c = 0; c < CH; ++c) v[c] = fmaf(f, sWlin[k * CH + c], v[c]);
    }

    int seg = idx[nidx];
    float wm = decf(wmaxb[seg]);           // segment nonempty (this point is in it)
    float e = expf(weight[nidx] - wm);
    unsafeAtomicAdd(denom + seg, e);
#pragma unroll
    for (int c = 0; c < CH; ++c)
        unsafeAtomicAdd(segsum + (size_t)seg * CH + c, e * v[c]);
}

// ------------------------------- segment pass --------------------------------
__global__ __launch_bounds__(256) void pass4_k(
    const unsigned* __restrict__ qmax, const unsigned* __restrict__ minb,
    const unsigned* __restrict__ cnt, const float* __restrict__ denom,
    const float* __restrict__ segsum,
    const float* __restrict__ Wfc1, const float* __restrict__ bfc1,
    const float* __restrict__ Wfc2, const float* __restrict__ bfc2,
    float* __restrict__ finalf) {
    __shared__ float sW1[CH * 64], sW2[64 * CH], sb1[64], sb2[CH];
    for (int i = threadIdx.x; i < CH * 64; i += blockDim.x) { sW1[i] = Wfc1[i]; sW2[i] = Wfc2[i]; }
    for (int i = threadIdx.x; i < 64; i += blockDim.x) sb1[i] = bfc1[i];
    for (int i = threadIdx.x; i < CH; i += blockDim.x) sb2[i] = bfc2[i];
    __syncthreads();

    int s = blockIdx.x * blockDim.x + threadIdx.x;
    if (s >= VSEG) return;

    float a1[64];
#pragma unroll
    for (int j = 0; j < 64; ++j) a1[j] = sb1[j];
#pragma unroll 4
    for (int c = 0; c < CH; ++c) {
        unsigned uu = minb[(size_t)s * CH + c];
        float f = (uu == ENC_POS_INF) ? 0.0f : decf(uu);
#pragma unroll
        for (int j = 0; j < 64; ++j) a1[j] = fmaf(f, sW1[c * 64 + j], a1[j]);
    }
#pragma unroll
    for (int j = 0; j < 64; ++j) a1[j] = fmaxf(a1[j], 0.0f);

    float dn = fmaxf(denom[s], 1e-16f);
    float ct = fmaxf((float)cnt[s], 1.0f);
    float inv_dc = 1.0f / (dn * ct);

    for (int c = 0; c < CH; ++c) {
        float z = sb2[c];
#pragma unroll
        for (int j = 0; j < 64; ++j) z = fmaf(a1[j], sW2[j * CH + c], z);
        float cw = 1.0f / (1.0f + expf(-z));
        float qm = __uint_as_float(qmax[(size_t)s * CH + c]);  // nonneg bits roundtrip
        float wx = segsum[(size_t)s * CH + c] * inv_dc;
        finalf[(size_t)s * CH + c] = cw * qm + (1.0f - cw) * wx;
    }
}

// ------------------------------- gather pass ---------------------------------
__global__ __launch_bounds__(256) void pass5_k(const int* __restrict__ idx, int n,
                                               const float* __restrict__ finalf,
                                               float* __restrict__ out) {
    int nidx = blockIdx.x * blockDim.x + threadIdx.x;
    if (nidx >= n) return;
    int seg = idx[nidx];
    const float4* fp = (const float4*)(finalf + (size_t)seg * CH);
    float4* op = (float4*)(out + (size_t)nidx * 64 + 32);
#pragma unroll
    for (int i = 0; i < 8; ++i) op[i] = fp[i];
}

// ------------------------------- launcher ------------------------------------
extern "C" void kernel_launch(void* const* d_in, const int* in_sizes, int n_in,
                              void* d_out, int out_size, void* d_ws, size_t ws_size,
                              hipStream_t stream) {
    const float* inputs = (const float*)d_in[0];
    const int*   unq    = (const int*)d_in[1];
    const float* Wlin = (const float*)d_in[3];
    const float* blin = (const float*)d_in[4];
    const float* g1   = (const float*)d_in[5];
    const float* be1  = (const float*)d_in[6];
    const float* Ww1  = (const float*)d_in[7];
    const float* bw1  = (const float*)d_in[8];
    const float* g2   = (const float*)d_in[9];
    const float* be2  = (const float*)d_in[10];
    const float* Ww2  = (const float*)d_in[11];
    const float* bw2  = (const float*)d_in[12];
    const float* Wfc1 = (const float*)d_in[13];
    const float* bfc1 = (const float*)d_in[14];
    const float* Wfc2 = (const float*)d_in[15];
    const float* bfc2 = (const float*)d_in[16];

    const int N = in_sizes[0] / KIN;
    float* out = (float*)d_out;

    char* ws = (char*)d_ws;
    size_t off = 0;
    auto alloc = [&](size_t bytes) -> void* {
        void* p = ws + off;
        off += (bytes + 255) & ~(size_t)255;
        return p;
    };
    unsigned* qmax   = (unsigned*)alloc((size_t)VSEG * CH * 4);
    unsigned* minb   = (unsigned*)alloc((size_t)VSEG * CH * 4);
    float*    segsum = (float*)   alloc((size_t)VSEG * CH * 4);
    float*    finalf = (float*)   alloc((size_t)VSEG * CH * 4);
    float*    denom  = (float*)   alloc((size_t)VSEG * 4);
    unsigned* cnt    = (unsigned*)alloc((size_t)VSEG * 4);
    unsigned* wmaxb  = (unsigned*)alloc((size_t)VSEG * 4);
    float*    ssbuf  = (float*)   alloc(128 * 4);
    float*    partial= (float*)   alloc((size_t)NB_STATS * 65 * 4);
    float*    weight = (float*)   alloc((size_t)N * 4);

    const int B = 256;
    int g_init = (VSEG * CH + B - 1) / B;
    int g_pt   = (N + B - 1) / B;
    int g_seg  = (VSEG + B - 1) / B;

    init_ws_k<<<g_init, B, 0, stream>>>(qmax, minb, segsum, denom, cnt, wmaxb);
    stats_partial_k<<<NB_STATS, B, 0, stream>>>(inputs, N, partial);
    stats_finalize_k<<<1, 128, 0, stream>>>(partial, NB_STATS, N,
                                            Wlin, blin, g1, be1, Ww1, bw1, g2, be2, ssbuf);
    pass2_k<<<g_pt, B, 0, stream>>>(inputs, unq, N, Wlin, blin, Ww1, bw1, Ww2, bw2,
                                    ssbuf, out, weight, qmax, minb, wmaxb, cnt);
    pass3_k<<<g_pt, B, 0, stream>>>(inputs, unq, N, Wlin, blin, weight, wmaxb, denom, segsum);
    pass4_k<<<g_seg, B, 0, stream>>>(qmax, minb, cnt, denom, segsum,
                                     Wfc1, bfc1, Wfc2, bfc2, finalf);
    pass5_k<<<g_pt, B, 0, stream>>>(unq, N, finalf, out);
}

// Round 2
// 1142.885 us; speedup vs baseline: 7.6725x; 7.6725x over previous
//
#include <hip/hip_runtime.h>
#include <math.h>

#define VSEG 50000
#define CH 32
#define KIN 10
#define NB_STATS 256

// ---------------------------- init workspace --------------------------------
__global__ __launch_bounds__(256) void init_cnt_k(unsigned* cnt) {
    int i = blockIdx.x * blockDim.x + threadIdx.x;
    if (i < VSEG) cnt[i] = 0u;
}

// ------------------------- stats: moments of inputs --------------------------
// acc layout: [0..9] = sum x_k ; [10..64] = sum x_k*x_l (k<=l), idx = 10 + k*(21-k)/2 + (l-k)
__global__ __launch_bounds__(256) void stats_partial_k(const float* __restrict__ in, int n,
                                                       float* __restrict__ partial) {
    float acc[65];
#pragma unroll
    for (int q = 0; q < 65; ++q) acc[q] = 0.0f;

    for (int i = blockIdx.x * blockDim.x + threadIdx.x; i < n; i += gridDim.x * blockDim.x) {
        const float* ip = in + (size_t)i * KIN;
        float x[KIN];
#pragma unroll
        for (int k = 0; k < KIN; ++k) x[k] = ip[k];
#pragma unroll
        for (int k = 0; k < KIN; ++k) acc[k] += x[k];
#pragma unroll
        for (int k = 0; k < KIN; ++k) {
#pragma unroll
            for (int l = k; l < KIN; ++l)
                acc[10 + k * (21 - k) / 2 + (l - k)] += x[k] * x[l];
        }
    }

    __shared__ float red[4][65];
    int lane = threadIdx.x & 63, wid = threadIdx.x >> 6;
#pragma unroll
    for (int q = 0; q < 65; ++q) {
        float v = acc[q];
#pragma unroll
        for (int off = 32; off > 0; off >>= 1) v += __shfl_down(v, off, 64);
        if (lane == 0) red[wid][q] = v;
    }
    __syncthreads();
    if (threadIdx.x < 65)
        partial[blockIdx.x * 65 + threadIdx.x] =
            red[0][threadIdx.x] + red[1][threadIdx.x] + red[2][threadIdx.x] + red[3][threadIdx.x];
}

// finalize: per-channel BN scale/shift for both branches.
// ss layout: [0..31]=scale_v [32..63]=shift_v [64..95]=scale_u [96..127]=shift_u
__global__ __launch_bounds__(128) void stats_finalize_k(
    const float* __restrict__ partial, int nb, int n,
    const float* __restrict__ Wlin, const float* __restrict__ blin,
    const float* __restrict__ g1, const float* __restrict__ be1,
    const float* __restrict__ Ww1, const float* __restrict__ bw1,
    const float* __restrict__ g2, const float* __restrict__ be2,
    float* __restrict__ ss) {
    __shared__ double tot[65];
    int t = threadIdx.x;
    if (t < 65) {
        double s = 0.0;
        for (int b = 0; b < nb; ++b) s += (double)partial[b * 65 + t];
        tot[t] = s;
    }
    __syncthreads();
    if (t < 64) {
        int c = t & 31;
        const float* W = (t < 32) ? Wlin : Ww1;
        double bb = (double)((t < 32) ? blin[c] : bw1[c]);
        double g  = (double)((t < 32) ? g1[c] : g2[c]);
        double be = (double)((t < 32) ? be1[c] : be2[c]);
        double eps = (t < 32) ? 1e-3 : 1e-5;
        double invN = 1.0 / (double)n;
        double m0 = 0.0;
        for (int k = 0; k < KIN; ++k) m0 += tot[k] * (double)W[k * CH + c];
        m0 *= invN;
        double q0 = 0.0;
        for (int k = 0; k < KIN; ++k)
            for (int l = k; l < KIN; ++l) {
                int qi = 10 + k * (21 - k) / 2 + (l - k);
                double coef = (k == l) ? 1.0 : 2.0;
                q0 += coef * tot[qi] * (double)W[k * CH + c] * (double)W[l * CH + c];
            }
        q0 *= invN;
        double var = q0 - m0 * m0;
        double mean = m0 + bb;
        double sc = g / sqrt(var + eps);
        float scale = (float)sc;
        float shift = (float)(be - mean * sc);
        if (t < 32) { ss[c] = scale; ss[32 + c] = shift; }
        else        { ss[64 + c] = scale; ss[96 + c] = shift; }
    }
}

// ---------------- point pass A: x -> out[:, :32], weight[N], histogram -------
__global__ __launch_bounds__(256) void passA_k(
    const float* __restrict__ in, const int* __restrict__ idx, int n,
    const float* __restrict__ Wlin, const float* __restrict__ blin,
    const float* __restrict__ Ww1, const float* __restrict__ bw1,
    const float* __restrict__ Ww2, const float* __restrict__ bw2,
    const float* __restrict__ ss,
    float* __restrict__ out, float* __restrict__ weight,
    unsigned* __restrict__ cnt) {
    __shared__ float sWlin[KIN * CH], sWw1[KIN * CH];
    __shared__ float sblin[CH], sbw1[CH], sWw2[CH], sss[128];
    __shared__ float sbw2;
    for (int i = threadIdx.x; i < KIN * CH; i += blockDim.x) { sWlin[i] = Wlin[i]; sWw1[i] = Ww1[i]; }
    for (int i = threadIdx.x; i < CH; i += blockDim.x) { sblin[i] = blin[i]; sbw1[i] = bw1[i]; sWw2[i] = Ww2[i]; }
    for (int i = threadIdx.x; i < 128; i += blockDim.x) sss[i] = ss[i];
    if (threadIdx.x == 0) sbw2 = bw2[0];
    __syncthreads();

    int nidx = blockIdx.x * blockDim.x + threadIdx.x;
    if (nidx >= n) return;

    const float* ip = in + (size_t)nidx * KIN;
    float x[KIN];
#pragma unroll
    for (int k = 0; k < KIN; ++k) x[k] = ip[k];

    float v[CH], u[CH];
#pragma unroll
    for (int c = 0; c < CH; ++c) { v[c] = sblin[c]; u[c] = sbw1[c]; }
#pragma unroll
    for (int k = 0; k < KIN; ++k) {
        float f = x[k];
#pragma unroll
        for (int c = 0; c < CH; ++c) {
            v[c] = fmaf(f, sWlin[k * CH + c], v[c]);
            u[c] = fmaf(f, sWw1[k * CH + c], u[c]);
        }
    }

    float w = sbw2;
    float xo[CH];
#pragma unroll
    for (int c = 0; c < CH; ++c) {
        float nv = fmaf(v[c], sss[c], sss[32 + c]);
        xo[c] = fmaxf(nv, 0.0f);
        float hu = fmaxf(fmaf(u[c], sss[64 + c], sss[96 + c]), 0.0f);
        w = fmaf(hu, sWw2[c], w);
    }

    float4* op = (float4*)(out + (size_t)nidx * 64);
#pragma unroll
    for (int c8 = 0; c8 < 8; ++c8)
        op[c8] = make_float4(xo[4 * c8], xo[4 * c8 + 1], xo[4 * c8 + 2], xo[4 * c8 + 3]);

    weight[nidx] = w;
    atomicAdd(&cnt[idx[nidx]], 1u);
}

// ------------------- exclusive prefix scan (single wave) ---------------------
__global__ __launch_bounds__(64) void prefix_k(const unsigned* __restrict__ cnt,
                                               unsigned* __restrict__ segstart,
                                               unsigned* __restrict__ woff) {
    int lane = threadIdx.x;
    unsigned running = 0;
    for (int base = 0; base < VSEG; base += 64) {
        int i = base + lane;
        unsigned v = (i < VSEG) ? cnt[i] : 0u;
        unsigned incl = v;
#pragma unroll
        for (int off = 1; off < 64; off <<= 1) {
            unsigned t = __shfl_up(incl, off, 64);
            if (lane >= off) incl += t;
        }
        unsigned excl = incl - v;
        if (i < VSEG) { segstart[i] = running + excl; woff[i] = running + excl; }
        running += __shfl(incl, 63, 64);
    }
}

// ------------------------------ scatter --------------------------------------
__global__ __launch_bounds__(256) void scatter_k(const int* __restrict__ idx, int n,
                                                 unsigned* __restrict__ woff,
                                                 int* __restrict__ sorted) {
    int i = blockIdx.x * blockDim.x + threadIdx.x;
    if (i >= n) return;
    unsigned p = atomicAdd(&woff[idx[i]], 1u);
    sorted[p] = i;
}

// ---------------- segmented reduction: one wave per segment ------------------
// lane = c + 32*h; lane handles channel c, points h, h+2, h+4, ...
__global__ __launch_bounds__(256) void reduce_k(
    const float* __restrict__ in, const int* __restrict__ sorted,
    const unsigned* __restrict__ segstart, const unsigned* __restrict__ cnt,
    const float* __restrict__ weight,
    const float* __restrict__ Wlin, const float* __restrict__ blin,
    const float* __restrict__ ss,
    float* __restrict__ qmaxf, float* __restrict__ minf,
    float* __restrict__ segsum, float* __restrict__ denomf) {
    __shared__ float sWlin[KIN * CH], sblin[CH], sss[64];
    for (int i = threadIdx.x; i < KIN * CH; i += blockDim.x) sWlin[i] = Wlin[i];
    for (int i = threadIdx.x; i < CH; i += blockDim.x) sblin[i] = blin[i];
    for (int i = threadIdx.x; i < 64; i += blockDim.x) sss[i] = ss[i];
    __syncthreads();

    int lane = threadIdx.x & 63;
    int c = lane & 31, h = lane >> 5;
    int wavesPerBlock = blockDim.x >> 6;
    int gw = blockIdx.x * wavesPerBlock + (threadIdx.x >> 6);
    int nW = gridDim.x * wavesPerBlock;

    float scale = sss[c], shift = sss[32 + c], bl = sblin[c];

    for (int seg = gw; seg < VSEG; seg += nW) {
        int m = (int)cnt[seg];
        size_t ob = (size_t)seg * CH + c;
        if (m == 0) {
            if (h == 0) { qmaxf[ob] = 0.0f; minf[ob] = 0.0f; segsum[ob] = 0.0f; }
            if (lane == 0) denomf[seg] = 0.0f;
            continue;
        }
        int base = (int)segstart[seg];

        float qm = 0.0f;                 // max relu(nv); >=0 for nonempty
        float mn = INFINITY;             // min nv
        float sm_m = -INFINITY, sm_d = 0.0f, sv = 0.0f;

        for (int p = h; p < m; p += 2) {
            int pi = sorted[base + p];
            const float* ip = in + (size_t)pi * KIN;
            float v = bl;
#pragma unroll
            for (int k = 0; k < KIN; ++k) v = fmaf(ip[k], sWlin[k * CH + c], v);
            float nv = fmaf(v, scale, shift);
            qm = fmaxf(qm, fmaxf(nv, 0.0f));
            mn = fminf(mn, nv);
            float w = weight[pi];
            if (w > sm_m) {
                float r = __expf(sm_m - w);   // exp(-inf)=0 on first point
                sm_d = fmaf(sm_d, r, 1.0f);
                sv = fmaf(sv, r, v);
                sm_m = w;
            } else {
                float t = __expf(w - sm_m);
                sm_d += t;
                sv = fmaf(t, v, sv);
            }
        }

        // merge the two halves (h=0 and h=1); empty half has sm_m=-inf, d=0, sv=0
        float oqm = __shfl_xor(qm, 32);
        float omn = __shfl_xor(mn, 32);
        float om  = __shfl_xor(sm_m, 32);
        float od  = __shfl_xor(sm_d, 32);
        float osv = __shfl_xor(sv, 32);
        qm = fmaxf(qm, oqm);
        mn = fminf(mn, omn);
        float M = fmaxf(sm_m, om);        // finite since m>=1
        float r1 = __expf(sm_m - M);      // 0 if this half empty
        float r2 = __expf(om - M);
        float d  = sm_d * r1 + od * r2;
        float S  = sv * r1 + osv * r2;

        if (h == 0) { qmaxf[ob] = qm; minf[ob] = mn; segsum[ob] = S; }
        if (lane == 0) denomf[seg] = d;
    }
}

// ------------------------------- segment pass --------------------------------
__global__ __launch_bounds__(256) void pass4_k(
    const float* __restrict__ qmaxf, const float* __restrict__ minf,
    const unsigned* __restrict__ cnt, const float* __restrict__ denomf,
    const float* __restrict__ segsum,
    const float* __restrict__ Wfc1, const float* __restrict__ bfc1,
    const float* __restrict__ Wfc2, const float* __restrict__ bfc2,
    float* __restrict__ finalf) {
    __shared__ float sW1[CH * 64], sW2[64 * CH], sb1[64], sb2[CH];
    for (int i = threadIdx.x; i < CH * 64; i += blockDim.x) { sW1[i] = Wfc1[i]; sW2[i] = Wfc2[i]; }
    for (int i = threadIdx.x; i < 64; i += blockDim.x) sb1[i] = bfc1[i];
    for (int i = threadIdx.x; i < CH; i += blockDim.x) sb2[i] = bfc2[i];
    __syncthreads();

    int s = blockIdx.x * blockDim.x + threadIdx.x;
    if (s >= VSEG) return;

    float a1[64];
#pragma unroll
    for (int j = 0; j < 64; ++j) a1[j] = sb1[j];
#pragma unroll 4
    for (int c = 0; c < CH; ++c) {
        float f = minf[(size_t)s * CH + c];
#pragma unroll
        for (int j = 0; j < 64; ++j) a1[j] = fmaf(f, sW1[c * 64 + j], a1[j]);
    }
#pragma unroll
    for (int j = 0; j < 64; ++j) a1[j] = fmaxf(a1[j], 0.0f);

    float dn = fmaxf(denomf[s], 1e-16f);
    float ct = fmaxf((float)cnt[s], 1.0f);
    float inv_dc = 1.0f / (dn * ct);

    for (int c = 0; c < CH; ++c) {
        float z = sb2[c];
#pragma unroll
        for (int j = 0; j < 64; ++j) z = fmaf(a1[j], sW2[j * CH + c], z);
        float cw = 1.0f / (1.0f + expf(-z));
        float qm = qmaxf[(size_t)s * CH + c];
        float wx = segsum[(size_t)s * CH + c] * inv_dc;
        finalf[(size_t)s * CH + c] = cw * qm + (1.0f - cw) * wx;
    }
}

// ------------------------------- gather pass ---------------------------------
__global__ __launch_bounds__(256) void pass5_k(const int* __restrict__ idx, int n,
                                               const float* __restrict__ finalf,
                                               float* __restrict__ out) {
    int nidx = blockIdx.x * blockDim.x + threadIdx.x;
    if (nidx >= n) return;
    int seg = idx[nidx];
    const float4* fp = (const float4*)(finalf + (size_t)seg * CH);
    float4* op = (float4*)(out + (size_t)nidx * 64 + 32);
#pragma unroll
    for (int i = 0; i < 8; ++i) op[i] = fp[i];
}

// ------------------------------- launcher ------------------------------------
extern "C" void kernel_launch(void* const* d_in, const int* in_sizes, int n_in,
                              void* d_out, int out_size, void* d_ws, size_t ws_size,
                              hipStream_t stream) {
    const float* inputs = (const float*)d_in[0];
    const int*   unq    = (const int*)d_in[1];
    const float* Wlin = (const float*)d_in[3];
    const float* blin = (const float*)d_in[4];
    const float* g1   = (const float*)d_in[5];
    const float* be1  = (const float*)d_in[6];
    const float* Ww1  = (const float*)d_in[7];
    const float* bw1  = (const float*)d_in[8];
    const float* g2   = (const float*)d_in[9];
    const float* be2  = (const float*)d_in[10];
    const float* Ww2  = (const float*)d_in[11];
    const float* bw2  = (const float*)d_in[12];
    const float* Wfc1 = (const float*)d_in[13];
    const float* bfc1 = (const float*)d_in[14];
    const float* Wfc2 = (const float*)d_in[15];
    const float* bfc2 = (const float*)d_in[16];

    const int N = in_sizes[0] / KIN;
    float* out = (float*)d_out;

    char* ws = (char*)d_ws;
    size_t off = 0;
    auto alloc = [&](size_t bytes) -> void* {
        void* p = ws + off;
        off += (bytes + 255) & ~(size_t)255;
        return p;
    };
    float*    qmaxf  = (float*)   alloc((size_t)VSEG * CH * 4);
    float*    minf   = (float*)   alloc((size_t)VSEG * CH * 4);
    float*    segsum = (float*)   alloc((size_t)VSEG * CH * 4);
    float*    finalf = (float*)   alloc((size_t)VSEG * CH * 4);
    float*    denomf = (float*)   alloc((size_t)VSEG * 4);
    unsigned* cnt    = (unsigned*)alloc((size_t)VSEG * 4);
    unsigned* segstart=(unsigned*)alloc((size_t)VSEG * 4);
    unsigned* woff   = (unsigned*)alloc((size_t)VSEG * 4);
    float*    ssbuf  = (float*)   alloc(128 * 4);
    float*    partial= (float*)   alloc((size_t)NB_STATS * 65 * 4);
    float*    weight = (float*)   alloc((size_t)N * 4);
    int*      sorted = (int*)     alloc((size_t)N * 4);

    const int B = 256;
    int g_pt  = (N + B - 1) / B;
    int g_seg = (VSEG + B - 1) / B;
    int g_red = (VSEG + 3) / 4;   // 4 waves/block, 1 wave per segment

    init_cnt_k<<<g_seg, B, 0, stream>>>(cnt);
    stats_partial_k<<<NB_STATS, B, 0, stream>>>(inputs, N, partial);
    stats_finalize_k<<<1, 128, 0, stream>>>(partial, NB_STATS, N,
                                            Wlin, blin, g1, be1, Ww1, bw1, g2, be2, ssbuf);
    passA_k<<<g_pt, B, 0, stream>>>(inputs, unq, N, Wlin, blin, Ww1, bw1, Ww2, bw2,
                                    ssbuf, out, weight, cnt);
    prefix_k<<<1, 64, 0, stream>>>(cnt, segstart, woff);
    scatter_k<<<g_pt, B, 0, stream>>>(unq, N, woff, sorted);
    reduce_k<<<g_red, B, 0, stream>>>(inputs, sorted, segstart, cnt, weight,
                                      Wlin, blin, ssbuf, qmaxf, minf, segsum, denomf);
    pass4_k<<<g_seg, B, 0, stream>>>(qmaxf, minf, cnt, denomf, segsum,
                                     Wfc1, bfc1, Wfc2, bfc2, finalf);
    pass5_k<<<g_pt, B, 0, stream>>>(unq, N, finalf, out);
}

// Round 3
// 674.790 us; speedup vs baseline: 12.9949x; 1.6937x over previous
//
#include <hip/hip_runtime.h>
#include <math.h>

#define VSEG 50000
#define CH 32
#define KIN 10
#define NB_STATS 256
#define SCAN_B 256
#define NBLK_SCAN ((VSEG + SCAN_B - 1) / SCAN_B)   // 196

// ---------------------------- init workspace --------------------------------
__global__ __launch_bounds__(256) void init_cnt_k(unsigned* cnt) {
    int i = blockIdx.x * blockDim.x + threadIdx.x;
    if (i < VSEG) cnt[i] = 0u;
}

// ---------------- stats: moments of inputs + segment histogram ---------------
// acc layout: [0..9] = sum x_k ; [10..64] = sum x_k*x_l (k<=l), idx = 10 + k*(21-k)/2 + (l-k)
__global__ __launch_bounds__(256) void stats_partial_k(const float* __restrict__ in,
                                                       const int* __restrict__ idx, int n,
                                                       float* __restrict__ partial,
                                                       unsigned* __restrict__ cnt) {
    float acc[65];
#pragma unroll
    for (int q = 0; q < 65; ++q) acc[q] = 0.0f;

    for (int i = blockIdx.x * blockDim.x + threadIdx.x; i < n; i += gridDim.x * blockDim.x) {
        const float* ip = in + (size_t)i * KIN;
        float x[KIN];
#pragma unroll
        for (int k = 0; k < KIN; ++k) x[k] = ip[k];
#pragma unroll
        for (int k = 0; k < KIN; ++k) acc[k] += x[k];
#pragma unroll
        for (int k = 0; k < KIN; ++k) {
#pragma unroll
            for (int l = k; l < KIN; ++l)
                acc[10 + k * (21 - k) / 2 + (l - k)] += x[k] * x[l];
        }
        atomicAdd(&cnt[idx[i]], 1u);
    }

    __shared__ float red[4][65];
    int lane = threadIdx.x & 63, wid = threadIdx.x >> 6;
#pragma unroll
    for (int q = 0; q < 65; ++q) {
        float v = acc[q];
#pragma unroll
        for (int off = 32; off > 0; off >>= 1) v += __shfl_down(v, off, 64);
        if (lane == 0) red[wid][q] = v;
    }
    __syncthreads();
    if (threadIdx.x < 65)
        partial[blockIdx.x * 65 + threadIdx.x] =
            red[0][threadIdx.x] + red[1][threadIdx.x] + red[2][threadIdx.x] + red[3][threadIdx.x];
}

// finalize: per-channel BN scale/shift for both branches.
// ss layout: [0..31]=scale_v [32..63]=shift_v [64..95]=scale_u [96..127]=shift_u
__global__ __launch_bounds__(128) void stats_finalize_k(
    const float* __restrict__ partial, int nb, int n,
    const float* __restrict__ Wlin, const float* __restrict__ blin,
    const float* __restrict__ g1, const float* __restrict__ be1,
    const float* __restrict__ Ww1, const float* __restrict__ bw1,
    const float* __restrict__ g2, const float* __restrict__ be2,
    float* __restrict__ ss) {
    __shared__ double tot[65];
    int t = threadIdx.x;
    if (t < 65) {
        double s = 0.0;
        for (int b = 0; b < nb; ++b) s += (double)partial[b * 65 + t];
        tot[t] = s;
    }
    __syncthreads();
    if (t < 64) {
        int c = t & 31;
        const float* W = (t < 32) ? Wlin : Ww1;
        double bb = (double)((t < 32) ? blin[c] : bw1[c]);
        double g  = (double)((t < 32) ? g1[c] : g2[c]);
        double be = (double)((t < 32) ? be1[c] : be2[c]);
        double eps = (t < 32) ? 1e-3 : 1e-5;
        double invN = 1.0 / (double)n;
        double m0 = 0.0;
        for (int k = 0; k < KIN; ++k) m0 += tot[k] * (double)W[k * CH + c];
        m0 *= invN;
        double q0 = 0.0;
        for (int k = 0; k < KIN; ++k)
            for (int l = k; l < KIN; ++l) {
                int qi = 10 + k * (21 - k) / 2 + (l - k);
                double coef = (k == l) ? 1.0 : 2.0;
                q0 += coef * tot[qi] * (double)W[k * CH + c] * (double)W[l * CH + c];
            }
        q0 *= invN;
        double var = q0 - m0 * m0;
        double mean = m0 + bb;
        double sc = g / sqrt(var + eps);
        float scale = (float)sc;
        float shift = (float)(be - mean * sc);
        if (t < 32) { ss[c] = scale; ss[32 + c] = shift; }
        else        { ss[64 + c] = scale; ss[96 + c] = shift; }
    }
}

// ------------------- hierarchical exclusive prefix scan ----------------------
__global__ __launch_bounds__(256) void scan1_k(const unsigned* __restrict__ cnt,
                                               unsigned* __restrict__ segstart,
                                               unsigned* __restrict__ bsum) {
    int t = threadIdx.x;
    int i = blockIdx.x * SCAN_B + t;
    unsigned v = (i < VSEG) ? cnt[i] : 0u;
    int lane = t & 63, w = t >> 6;
    unsigned incl = v;
#pragma unroll
    for (int off = 1; off < 64; off <<= 1) {
        unsigned s = __shfl_up(incl, off, 64);
        if (lane >= off) incl += s;
    }
    __shared__ unsigned wsum[4];
    if (lane == 63) wsum[w] = incl;
    __syncthreads();
    unsigned wo = 0;
#pragma unroll
    for (int k = 0; k < 4; ++k) wo += (k < w) ? wsum[k] : 0u;
    if (i < VSEG) segstart[i] = wo + incl - v;     // block-local exclusive
    if (t == SCAN_B - 1) bsum[blockIdx.x] = wo + incl;
}

__global__ __launch_bounds__(256) void scan2_k(unsigned* __restrict__ bsum, int nb) {
    int t = threadIdx.x;
    unsigned v = (t < nb) ? bsum[t] : 0u;
    int lane = t & 63, w = t >> 6;
    unsigned incl = v;
#pragma unroll
    for (int off = 1; off < 64; off <<= 1) {
        unsigned s = __shfl_up(incl, off, 64);
        if (lane >= off) incl += s;
    }
    __shared__ unsigned wsum[4];
    if (lane == 63) wsum[w] = incl;
    __syncthreads();
    unsigned wo = 0;
#pragma unroll
    for (int k = 0; k < 4; ++k) wo += (k < w) ? wsum[k] : 0u;
    if (t < nb) bsum[t] = wo + incl - v;           // exclusive, in place
}

__global__ __launch_bounds__(256) void scan3_k(unsigned* __restrict__ segstart,
                                               const unsigned* __restrict__ bsum,
                                               unsigned* __restrict__ woff) {
    int i = blockIdx.x * SCAN_B + threadIdx.x;
    if (i < VSEG) {
        unsigned s = segstart[i] + bsum[blockIdx.x];
        segstart[i] = s;
        woff[i] = s;
    }
}

// ------- point pass A: x -> out[:, :32], weight[N], scatter into sorted ------
__global__ __launch_bounds__(256) void passA_k(
    const float* __restrict__ in, const int* __restrict__ idx, int n,
    const float* __restrict__ Wlin, const float* __restrict__ blin,
    const float* __restrict__ Ww1, const float* __restrict__ bw1,
    const float* __restrict__ Ww2, const float* __restrict__ bw2,
    const float* __restrict__ ss,
    float* __restrict__ out, float* __restrict__ weight,
    unsigned* __restrict__ woff, int* __restrict__ sorted) {
    __shared__ float sWlin[KIN * CH], sWw1[KIN * CH];
    __shared__ float sblin[CH], sbw1[CH], sWw2[CH], sss[128];
    __shared__ float sbw2;
    for (int i = threadIdx.x; i < KIN * CH; i += blockDim.x) { sWlin[i] = Wlin[i]; sWw1[i] = Ww1[i]; }
    for (int i = threadIdx.x; i < CH; i += blockDim.x) { sblin[i] = blin[i]; sbw1[i] = bw1[i]; sWw2[i] = Ww2[i]; }
    for (int i = threadIdx.x; i < 128; i += blockDim.x) sss[i] = ss[i];
    if (threadIdx.x == 0) sbw2 = bw2[0];
    __syncthreads();

    int nidx = blockIdx.x * blockDim.x + threadIdx.x;
    if (nidx >= n) return;

    const float* ip = in + (size_t)nidx * KIN;
    float x[KIN];
#pragma unroll
    for (int k = 0; k < KIN; ++k) x[k] = ip[k];

    float v[CH], u[CH];
#pragma unroll
    for (int c = 0; c < CH; ++c) { v[c] = sblin[c]; u[c] = sbw1[c]; }
#pragma unroll
    for (int k = 0; k < KIN; ++k) {
        float f = x[k];
#pragma unroll
        for (int c = 0; c < CH; ++c) {
            v[c] = fmaf(f, sWlin[k * CH + c], v[c]);
            u[c] = fmaf(f, sWw1[k * CH + c], u[c]);
        }
    }

    float w = sbw2;
    float xo[CH];
#pragma unroll
    for (int c = 0; c < CH; ++c) {
        float nv = fmaf(v[c], sss[c], sss[32 + c]);
        xo[c] = fmaxf(nv, 0.0f);
        float hu = fmaxf(fmaf(u[c], sss[64 + c], sss[96 + c]), 0.0f);
        w = fmaf(hu, sWw2[c], w);
    }

    float4* op = (float4*)(out + (size_t)nidx * 64);
#pragma unroll
    for (int c8 = 0; c8 < 8; ++c8)
        op[c8] = make_float4(xo[4 * c8], xo[4 * c8 + 1], xo[4 * c8 + 2], xo[4 * c8 + 3]);

    weight[nidx] = w;
    unsigned p = atomicAdd(&woff[idx[nidx]], 1u);
    sorted[p] = nidx;
}

// ---------------- segmented reduction: one wave per segment ------------------
// lane = c + 32*h; lane handles channel c, points h, h+2, h+4, ...
__global__ __launch_bounds__(256) void reduce_k(
    const float* __restrict__ in, const int* __restrict__ sorted,
    const unsigned* __restrict__ segstart, const unsigned* __restrict__ cnt,
    const float* __restrict__ weight,
    const float* __restrict__ Wlin, const float* __restrict__ blin,
    const float* __restrict__ ss,
    float* __restrict__ qmaxf, float* __restrict__ minf,
    float* __restrict__ segsum, float* __restrict__ denomf) {
    __shared__ float sWlin[KIN * CH], sblin[CH], sss[64];
    for (int i = threadIdx.x; i < KIN * CH; i += blockDim.x) sWlin[i] = Wlin[i];
    for (int i = threadIdx.x; i < CH; i += blockDim.x) sblin[i] = blin[i];
    for (int i = threadIdx.x; i < 64; i += blockDim.x) sss[i] = ss[i];
    __syncthreads();

    int lane = threadIdx.x & 63;
    int c = lane & 31, h = lane >> 5;
    int wavesPerBlock = blockDim.x >> 6;
    int gw = blockIdx.x * wavesPerBlock + (threadIdx.x >> 6);
    int nW = gridDim.x * wavesPerBlock;

    float scale = sss[c], shift = sss[32 + c], bl = sblin[c];

    for (int seg = gw; seg < VSEG; seg += nW) {
        int m = (int)cnt[seg];
        size_t ob = (size_t)seg * CH + c;
        if (m == 0) {
            if (h == 0) { qmaxf[ob] = 0.0f; minf[ob] = 0.0f; segsum[ob] = 0.0f; }
            if (lane == 0) denomf[seg] = 0.0f;
            continue;
        }
        int base = (int)segstart[seg];

        float qm = 0.0f;                 // max relu(nv); >=0 for nonempty
        float mn = INFINITY;             // min nv
        float sm_m = -INFINITY, sm_d = 0.0f, sv = 0.0f;

        for (int p = h; p < m; p += 2) {
            int pi = sorted[base + p];
            const float* ip = in + (size_t)pi * KIN;
            float v = bl;
#pragma unroll
            for (int k = 0; k < KIN; ++k) v = fmaf(ip[k], sWlin[k * CH + c], v);
            float nv = fmaf(v, scale, shift);
            qm = fmaxf(qm, fmaxf(nv, 0.0f));
            mn = fminf(mn, nv);
            float w = weight[pi];
            if (w > sm_m) {
                float r = __expf(sm_m - w);   // exp(-inf)=0 on first point
                sm_d = fmaf(sm_d, r, 1.0f);
                sv = fmaf(sv, r, v);
                sm_m = w;
            } else {
                float t = __expf(w - sm_m);
                sm_d += t;
                sv = fmaf(t, v, sv);
            }
        }

        // merge the two halves (h=0 and h=1); empty half has sm_m=-inf, d=0, sv=0
        float oqm = __shfl_xor(qm, 32);
        float omn = __shfl_xor(mn, 32);
        float om  = __shfl_xor(sm_m, 32);
        float od  = __shfl_xor(sm_d, 32);
        float osv = __shfl_xor(sv, 32);
        qm = fmaxf(qm, oqm);
        mn = fminf(mn, omn);
        float M = fmaxf(sm_m, om);        // finite since m>=1
        float r1 = __expf(sm_m - M);      // 0 if this half empty
        float r2 = __expf(om - M);
        float d  = sm_d * r1 + od * r2;
        float S  = sv * r1 + osv * r2;

        if (h == 0) { qmaxf[ob] = qm; minf[ob] = mn; segsum[ob] = S; }
        if (lane == 0) denomf[seg] = d;
    }
}

// ------------------------------- segment pass --------------------------------
__global__ __launch_bounds__(256) void pass4_k(
    const float* __restrict__ qmaxf, const float* __restrict__ minf,
    const unsigned* __restrict__ cnt, const float* __restrict__ denomf,
    const float* __restrict__ segsum,
    const float* __restrict__ Wfc1, const float* __restrict__ bfc1,
    const float* __restrict__ Wfc2, const float* __restrict__ bfc2,
    float* __restrict__ finalf) {
    __shared__ float sW1[CH * 64], sW2[64 * CH], sb1[64], sb2[CH];
    for (int i = threadIdx.x; i < CH * 64; i += blockDim.x) { sW1[i] = Wfc1[i]; sW2[i] = Wfc2[i]; }
    for (int i = threadIdx.x; i < 64; i += blockDim.x) sb1[i] = bfc1[i];
    for (int i = threadIdx.x; i < CH; i += blockDim.x) sb2[i] = bfc2[i];
    __syncthreads();

    int s = blockIdx.x * blockDim.x + threadIdx.x;
    if (s >= VSEG) return;

    float a1[64];
#pragma unroll
    for (int j = 0; j < 64; ++j) a1[j] = sb1[j];
#pragma unroll 4
    for (int c = 0; c < CH; ++c) {
        float f = minf[(size_t)s * CH + c];
#pragma unroll
        for (int j = 0; j < 64; ++j) a1[j] = fmaf(f, sW1[c * 64 + j], a1[j]);
    }
#pragma unroll
    for (int j = 0; j < 64; ++j) a1[j] = fmaxf(a1[j], 0.0f);

    float dn = fmaxf(denomf[s], 1e-16f);
    float ct = fmaxf((float)cnt[s], 1.0f);
    float inv_dc = 1.0f / (dn * ct);

    for (int c = 0; c < CH; ++c) {
        float z = sb2[c];
#pragma unroll
        for (int j = 0; j < 64; ++j) z = fmaf(a1[j], sW2[j * CH + c], z);
        float cw = 1.0f / (1.0f + expf(-z));
        float qm = qmaxf[(size_t)s * CH + c];
        float wx = segsum[(size_t)s * CH + c] * inv_dc;
        finalf[(size_t)s * CH + c] = cw * qm + (1.0f - cw) * wx;
    }
}

// ------------------------------- gather pass ---------------------------------
__global__ __launch_bounds__(256) void pass5_k(const int* __restrict__ idx, int n,
                                               const float* __restrict__ finalf,
                                               float* __restrict__ out) {
    int nidx = blockIdx.x * blockDim.x + threadIdx.x;
    if (nidx >= n) return;
    int seg = idx[nidx];
    const float4* fp = (const float4*)(finalf + (size_t)seg * CH);
    float4* op = (float4*)(out + (size_t)nidx * 64 + 32);
#pragma unroll
    for (int i = 0; i < 8; ++i) op[i] = fp[i];
}

// ------------------------------- launcher ------------------------------------
extern "C" void kernel_launch(void* const* d_in, const int* in_sizes, int n_in,
                              void* d_out, int out_size, void* d_ws, size_t ws_size,
                              hipStream_t stream) {
    const float* inputs = (const float*)d_in[0];
    const int*   unq    = (const int*)d_in[1];
    const float* Wlin = (const float*)d_in[3];
    const float* blin = (const float*)d_in[4];
    const float* g1   = (const float*)d_in[5];
    const float* be1  = (const float*)d_in[6];
    const float* Ww1  = (const float*)d_in[7];
    const float* bw1  = (const float*)d_in[8];
    const float* g2   = (const float*)d_in[9];
    const float* be2  = (const float*)d_in[10];
    const float* Ww2  = (const float*)d_in[11];
    const float* bw2  = (const float*)d_in[12];
    const float* Wfc1 = (const float*)d_in[13];
    const float* bfc1 = (const float*)d_in[14];
    const float* Wfc2 = (const float*)d_in[15];
    const float* bfc2 = (const float*)d_in[16];

    const int N = in_sizes[0] / KIN;
    float* out = (float*)d_out;

    char* ws = (char*)d_ws;
    size_t off = 0;
    auto alloc = [&](size_t bytes) -> void* {
        void* p = ws + off;
        off += (bytes + 255) & ~(size_t)255;
        return p;
    };
    float*    qmaxf  = (float*)   alloc((size_t)VSEG * CH * 4);
    float*    minf   = (float*)   alloc((size_t)VSEG * CH * 4);
    float*    segsum = (float*)   alloc((size_t)VSEG * CH * 4);
    float*    finalf = (float*)   alloc((size_t)VSEG * CH * 4);
    float*    denomf = (float*)   alloc((size_t)VSEG * 4);
    unsigned* cnt    = (unsigned*)alloc((size_t)VSEG * 4);
    unsigned* segstart=(unsigned*)alloc((size_t)VSEG * 4);
    unsigned* woff   = (unsigned*)alloc((size_t)VSEG * 4);
    unsigned* bsum   = (unsigned*)alloc((size_t)NBLK_SCAN * 4);
    float*    ssbuf  = (float*)   alloc(128 * 4);
    float*    partial= (float*)   alloc((size_t)NB_STATS * 65 * 4);
    float*    weight = (float*)   alloc((size_t)N * 4);
    int*      sorted = (int*)     alloc((size_t)N * 4);

    const int B = 256;
    int g_pt  = (N + B - 1) / B;
    int g_seg = (VSEG + B - 1) / B;
    int g_red = (VSEG + 3) / 4;   // 4 waves/block, 1 wave per segment

    init_cnt_k<<<g_seg, B, 0, stream>>>(cnt);
    stats_partial_k<<<NB_STATS, B, 0, stream>>>(inputs, unq, N, partial, cnt);
    stats_finalize_k<<<1, 128, 0, stream>>>(partial, NB_STATS, N,
                                            Wlin, blin, g1, be1, Ww1, bw1, g2, be2, ssbuf);
    scan1_k<<<NBLK_SCAN, SCAN_B, 0, stream>>>(cnt, segstart, bsum);
    scan2_k<<<1, SCAN_B, 0, stream>>>(bsum, NBLK_SCAN);
    scan3_k<<<NBLK_SCAN, SCAN_B, 0, stream>>>(segstart, bsum, woff);
    passA_k<<<g_pt, B, 0, stream>>>(inputs, unq, N, Wlin, blin, Ww1, bw1, Ww2, bw2,
                                    ssbuf, out, weight, woff, sorted);
    reduce_k<<<g_red, B, 0, stream>>>(inputs, sorted, segstart, cnt, weight,
                                      Wlin, blin, ssbuf, qmaxf, minf, segsum, denomf);
    pass4_k<<<g_seg, B, 0, stream>>>(qmaxf, minf, cnt, denomf, segsum,
                                     Wfc1, bfc1, Wfc2, bfc2, finalf);
    pass5_k<<<g_pt, B, 0, stream>>>(unq, N, finalf, out);
}